// Round 12
// baseline (120.261 us; speedup 1.0000x reference)
//
#include <hip/hip_runtime.h>
#include <math.h>

#define NUM_E   100000
#define GAMMA_F 12.0f
#define EMB_RANGE_F 0.21875f                       // (12+2)/64
#define INV_TWO_EMB (1.0f / (2.0f * EMB_RANGE_F))  // rev = r * this = phase/(2pi)

#define TILE_E  8                                  // entities per wave-tile (4 KB)
#define NTIL    (NUM_E / TILE_E)                   // 12500 tiles exactly
#define GRIDB   1280                               // 5 blocks/CU (LDS-capped)

typedef float v4f __attribute__((ext_vector_type(4)));
typedef float v2f __attribute__((ext_vector_type(2)));

// ---- packed-f32 VALU (VOP3P): 2 dims per instruction ----
static __device__ __forceinline__ v2f pk_sub(v2f a, v2f b) {
    v2f d;
    asm("v_pk_add_f32 %0, %1, %2 neg_lo:[0,1] neg_hi:[0,1]"
        : "=v"(d) : "v"(a), "v"(b));
    return d;
}
static __device__ __forceinline__ v2f pk_mul(v2f a, v2f b) {
    v2f d;
    asm("v_pk_mul_f32 %0, %1, %2" : "=v"(d) : "v"(a), "v"(b));
    return d;
}
static __device__ __forceinline__ v2f pk_fma(v2f a, v2f b, v2f c) {
    v2f d;
    asm("v_pk_fma_f32 %0, %1, %2, %3" : "=v"(d) : "v"(a), "v"(b), "v"(c));
    return d;
}
static __device__ __forceinline__ float sq2(v2f dx, v2f dy) {
    v2f sq = pk_fma(dy, dy, pk_mul(dx, dx));
    return __builtin_amdgcn_sqrtf(sq.x) + __builtin_amdgcn_sqrtf(sq.y);
}
static __device__ __forceinline__ v2f lo2(v4f v) { return __builtin_shufflevector(v, v, 0, 1); }
static __device__ __forceinline__ v2f hi2(v4f v) { return __builtin_shufflevector(v, v, 2, 3); }

// cross-lane add via DPP (VALU pipe, no DS, no lgkm wait)
// 0xB1 = quad_perm [1,0,3,2] (xor1), 0x4E = quad_perm [2,3,0,1] (xor2),
// 0x141 = row_half_mirror: after xor1+xor2 it adds the other quad of the
// aligned 8-lane group. Verified passing R8-R17.
template <int CTRL>
static __device__ __forceinline__ float dpp_xor_add(float x) {
    int y = __builtin_amdgcn_update_dpp(0, __float_as_int(x), CTRL, 0xF, 0xF, true);
    return x + __int_as_float(y);
}

// distance for ONE entity vs this lane's 1 batch x 8 dims, reduced over the
// 8 dg lanes of the batch-group (all 8 lanes end with the result)
static __device__ __forceinline__ float dist_entity(
        v4f er0, v4f er1, v4f ei0, v4f ei1,
        const v2f RR[4], const v2f RI[4]) {
    v2f e2[4] = { lo2(er0), hi2(er0), lo2(er1), hi2(er1) };
    v2f i2[4] = { lo2(ei0), hi2(ei0), lo2(ei1), hi2(ei1) };
    float s0 = sq2(pk_sub(RR[0], e2[0]), pk_sub(RI[0], i2[0]));
    float s1 = sq2(pk_sub(RR[1], e2[1]), pk_sub(RI[1], i2[1]));
    float s2 = sq2(pk_sub(RR[2], e2[2]), pk_sub(RI[2], i2[2]));
    float s3 = sq2(pk_sub(RR[3], e2[3]), pk_sub(RI[3], i2[3]));
    float v = (s0 + s1) + (s2 + s3);
    v = dpp_xor_add<0xB1>(v);            // xor1 (within quad)
    v = dpp_xor_add<0x4E>(v);            // xor2 (within quad)
    v = dpp_xor_add<0x141>(v);           // xor4 via row_half_mirror
    return GAMMA_F - v;
}

// async global->LDS DMA, width 16: 64 lanes x 16B = 1 KB per instruction.
// Per-lane global src; wave-uniform LDS base (HW adds lane*16B). No dest
// register -> the allocator cannot sink/compress the pipeline (R11-R14).
static __device__ __forceinline__ void stage_chunk(const float* g, float* l) {
    __builtin_amdgcn_global_load_lds(
        (const __attribute__((address_space(1))) void*)g,
        (__attribute__((address_space(3))) void*)l,
        16, 0, 0);
}

// this lane's rot slice for one batch (8 dims x {re,im} = 16 f32).
// sin/cos-produced -> NOT rematerializable: stays register-resident.
static __device__ __forceinline__ void make_rot(
        const int* __restrict__ facts, const float* __restrict__ ent,
        const float* __restrict__ rel, int b, int dg, v2f RR[4], v2f RI[4]) {
    const int f0 = facts[b * 3 + 0];
    const int f1 = facts[b * 3 + 1];
    const float* hp = ent + (size_t)f0 * 128 + dg * 8;
    const float* rp = rel + (size_t)f1 * 64  + dg * 8;
    v4f hre0 = *(const v4f*)(hp);
    v4f hre1 = *(const v4f*)(hp + 4);
    v4f him0 = *(const v4f*)(hp + 64);
    v4f him1 = *(const v4f*)(hp + 68);
    v4f ph0  = *(const v4f*)(rp);
    v4f ph1  = *(const v4f*)(rp + 4);
    v4f rr0, rr1, ri0, ri1;
#pragma unroll
    for (int j = 0; j < 4; ++j) {
        float rev0 = ph0[j] * INV_TWO_EMB;       // phase/(2pi) in [-0.5,0.5]
        float s0 = __builtin_amdgcn_sinf(rev0);  // v_sin_f32: revolutions
        float c0 = __builtin_amdgcn_cosf(rev0);
        rr0[j] = hre0[j] * c0 - him0[j] * s0;
        ri0[j] = hre0[j] * s0 + him0[j] * c0;
        float rev1 = ph1[j] * INV_TWO_EMB;
        float s1 = __builtin_amdgcn_sinf(rev1);
        float c1 = __builtin_amdgcn_cosf(rev1);
        rr1[j] = hre1[j] * c1 - him1[j] * s1;
        ri1[j] = hre1[j] * s1 + him1[j] * c1;
    }
    RR[0] = lo2(rr0); RR[1] = hi2(rr0); RR[2] = lo2(rr1); RR[3] = hi2(rr1);
    RI[0] = lo2(ri0); RI[1] = hi2(ri0); RI[2] = lo2(ri1); RI[3] = hi2(ri1);
}

// R18: BARRIER-FREE wave-independent streams.
// R15-R17 ledger: LDS reads are 8-address broadcast + 2-way bank alias =
// ~free (R17's read-halving regressed; m136 says 2-way is 1.02x) -> DS pipe
// was never the binder. Busy = ~26us (VALU ~10 + trans ~10 + misc), wall 43,
// stall 17us (39%). Intra-wave LDS latency excluded (R16 lookahead +1.4%).
// Remaining structural suspect: two __syncthreads per tile couple the 4
// waves; each barrier drains vmcnt(0)+lgkmcnt(0) (the documented m97 ~20%
// stall mechanism) and compounds wave-skew across 8 co-resident blocks.
// Fix: each wave = an independent stream. Wave wv owns batch-group wv (rot
// 16 f32/lane, the proven-resident config), stages ITS OWN copy of each
// 8-entity tile into its private LDS quarter (4 chunks), and syncs with a
// per-wave `s_waitcnt vmcnt(0)` only. NO __syncthreads in the kernel.
// The block's 4 waves walk the same tiles -> 4x staging is L2-local (same
// XCD), HBM FETCH unchanged. 32KB LDS/block -> 5 blocks/CU, 20 waves/CU;
// ~880cy compute/flip ~ HBM latency, residual covered by 5 waves/SIMD of
// UNCOUPLED progress. sched_barrier(0) pins DMA issue above compute.
__global__ __launch_bounds__(256, 2) void rotate_dist_fused(
        const int*   __restrict__ facts,
        const float* __restrict__ ent,
        const float* __restrict__ rel,
        float*       __restrict__ out) {
    __shared__ __align__(16) float sbuf[4][2][TILE_E * 128];   // 4 x 2 x 4 KB

    const int t    = threadIdx.x;
    const int lane = t & 63;
    const int wv   = t >> 6;
    const int bq   = lane >> 3;         // batch-in-group 0..7
    const int dg   = lane & 7;          // dims 8dg..8dg+7
    const int b    = wv * 8 + bq;       // this lane's batch row

    int tile = blockIdx.x;

    // ---- stage first tile into this wave's buf0 ----
    {
        const float* g = ent + (size_t)tile * (TILE_E * 128) + lane * 4;
        float* l = &sbuf[wv][0][0];
#pragma unroll
        for (int c = 0; c < 4; ++c) stage_chunk(g + c * 256, l + c * 256);
    }
    __builtin_amdgcn_sched_barrier(0);

    // ---- rot slice in registers (hides the first DMA's latency) ----
    v2f RR[4], RI[4];
    make_rot(facts, ent, rel, b, dg, RR, RI);

    float* orow = out + (size_t)b * NUM_E;

    asm volatile("s_waitcnt vmcnt(0)" ::: "memory");   // buf0 landed (per-wave)
    __builtin_amdgcn_sched_barrier(0);

    int cur = 0;
    while (true) {
        const int nxt = tile + GRIDB;
        if (nxt < NTIL) {   // issue next-tile DMA before computing current
            const float* g = ent + (size_t)nxt * (TILE_E * 128) + lane * 4;
            float* l = &sbuf[wv][cur ^ 1][0];
#pragma unroll
            for (int c = 0; c < 4; ++c) stage_chunk(g + c * 256, l + c * 256);
        }
        __builtin_amdgcn_sched_barrier(0);   // DMA stays issued above compute

        // ---- compute current tile from this wave's private LDS ----
        const float* csrc = &sbuf[wv][cur][0] + dg * 8;
        const int e0 = tile * TILE_E;
        v4f vout0, vout1;
#pragma unroll
        for (int i = 0; i < 8; ++i) {
            const float* ep = csrc + i * 128;
            v4f er0 = *(const v4f*)(ep);         // ds_read_b128, 8-addr bcast
            v4f er1 = *(const v4f*)(ep + 4);
            v4f ei0 = *(const v4f*)(ep + 64);
            v4f ei1 = *(const v4f*)(ep + 68);
            float r = dist_entity(er0, er1, ei0, ei1, RR, RI);
            if (i < 4) vout0[i] = r; else vout1[i - 4] = r;
        }
        // all dg lanes hold all 8 results; disjoint 16B-coalesced stores
        if (dg == 0) *(v4f*)(orow + e0)     = vout0;
        if (dg == 1) *(v4f*)(orow + e0 + 4) = vout1;

        if (nxt >= NTIL) break;
        asm volatile("s_waitcnt vmcnt(0)" ::: "memory");   // next buf landed
        __builtin_amdgcn_sched_barrier(0);
        cur ^= 1;
        tile = nxt;
    }
}

extern "C" void kernel_launch(void* const* d_in, const int* in_sizes, int n_in,
                              void* d_out, int out_size, void* d_ws, size_t ws_size,
                              hipStream_t stream) {
    const int*   facts = (const int*)d_in[0];
    const float* ent   = (const float*)d_in[1];
    const float* rel   = (const float*)d_in[2];
    float*       out   = (float*)d_out;
    (void)d_ws; (void)ws_size;

    rotate_dist_fused<<<dim3(GRIDB), dim3(256), 0, stream>>>(facts, ent, rel, out);
}